// Round 2
// baseline (446.943 us; speedup 1.0000x reference)
//
#include <hip/hip_runtime.h>

// ---------------- problem constants ----------------
#define N13E 16224      // 32*3*169
#define N26E 64896      // 32*3*676
#define NTOT 340704
#define BASE26 16224
#define BASE52 81120
#define KMAX 2048
#define TOPK 512

__device__ __forceinline__ float sigm(float x) { return 1.0f / (1.0f + expf(-x)); }

// ================= K1: histogram of conf bits (R3-validated, round-0 verbatim) =================
template <int HW>
__device__ __forceinline__ float load_logit(const float* __restrict__ p, int local) {
    int ba = local / HW;           // b*3 + a
    int hw = local - ba * HW;
    int b = ba / 3;
    int a = ba - b * 3;
    return p[(b * 255 + a * 85 + 4) * HW + hw];
}

__global__ void __launch_bounds__(256) k_hist(const float* __restrict__ p13,
                                              const float* __restrict__ p26,
                                              const float* __restrict__ p52,
                                              unsigned* __restrict__ hist) {
    int t = blockIdx.x * 256 + threadIdx.x;
    if (t >= NTOT) return;
    float logit;
    if (t < N13E)               logit = load_logit<169>(p13, t);
    else if (t < N13E + N26E)   logit = load_logit<676>(p26, t - N13E);
    else                        logit = load_logit<2704>(p52, t - (N13E + N26E));
    float conf = sigm(logit);
    if (conf > 0.5f) {
        unsigned bin = (__float_as_uint(conf) >> 12) - 0x3F000u;
        bin = (bin > 2047u) ? 2047u : bin;
        atomicAdd(&hist[bin], 1u);
    }
}

// ================= K2: per-block threshold scan + compact (R3-validated, round-0 verbatim) =================
template <int HW, int BASE>
__device__ __forceinline__ void compact_one(const float* __restrict__ p, int local, unsigned thrv,
                                            unsigned* __restrict__ cnt,
                                            unsigned long long* __restrict__ keys) {
    int ba = local / HW;
    int hw = local - ba * HW;
    int b = ba / 3;
    int a = ba - b * 3;
    float logit = p[(b * 255 + a * 85 + 4) * HW + hw];
    float conf = sigm(logit);
    unsigned bits = __float_as_uint(conf);
    if (conf > 0.5f && bits >= thrv) {
        unsigned pos = atomicAdd(cnt, 1u);
        if (pos < (unsigned)KMAX) {
            unsigned concat = (unsigned)(BASE + (b * HW + hw) * 3 + a);
            keys[pos] = (((unsigned long long)bits) << 32) | (unsigned long long)(0xFFFFFFFFu - concat);
        }
    }
}

__global__ void __launch_bounds__(512) k_compact_scan(const float* __restrict__ p13,
                                                      const float* __restrict__ p26,
                                                      const float* __restrict__ p52,
                                                      const unsigned* __restrict__ hist,
                                                      unsigned* __restrict__ cnt,
                                                      unsigned long long* __restrict__ keys) {
    __shared__ unsigned tot[512];
    __shared__ unsigned thrS;
    int tid = threadIdx.x;

    unsigned loc[4]; unsigned s = 0u;
#pragma unroll
    for (int k = 0; k < 4; ++k) { loc[k] = hist[2047 - (tid * 4 + k)]; s += loc[k]; }
    tot[tid] = s;
    __syncthreads();
    for (int off = 1; off < 512; off <<= 1) {
        unsigned u = (tid >= off) ? tot[tid - off] : 0u;
        __syncthreads();
        tot[tid] += u;
        __syncthreads();
    }
    unsigned excl = tot[tid] - s;
    unsigned total = tot[511];
    if (total < (unsigned)TOPK) {
        if (tid == 0) thrS = 0x3F000001u;     // accept every conf > 0.5
    } else {
        unsigned run = excl;
#pragma unroll
        for (int k = 0; k < 4; ++k) {
            unsigned c = run + loc[k];
            if (run < (unsigned)TOPK && c >= (unsigned)TOPK) {  // unique crossing
                int bin = 2047 - (tid * 4 + k);
                thrS = ((unsigned)(bin + 0x3F000)) << 12;
            }
            run = c;
        }
    }
    __syncthreads();
    unsigned thrv = thrS;

    int t = blockIdx.x * 512 + tid;
    if (t >= NTOT) return;
    if (t < N13E)               compact_one<169, 0>(p13, t, thrv, cnt, keys);
    else if (t < N13E + N26E)   compact_one<676, BASE26>(p26, t - N13E, thrv, cnt, keys);
    else                        compact_one<2704, BASE52>(p52, t - (N13E + N26E), thrv, cnt, keys);
}

// ================= K3 mega: rank + decode + mask + sweep, ONE block =================
// Decode: one THREAD per box (not 64 lanes) — 80 independent class loads give MLP,
// avoids needing 32K lanes. Argmax semantics match pack_key: ascending c with strict >
// keeps the first (smallest-class) maximum, same as jnp.argmax tie rule.
template <int HW, int W>
__device__ __forceinline__ void decode1(const float* __restrict__ p, int local, float strideF,
                                        float aw0, float ah0, float aw1, float ah1, float aw2, float ah2,
                                        float conf, float* __restrict__ row) {
    int a = local % 3;
    int cell = local / 3;
    int b = cell / HW;
    int hw = cell - b * HW;
    int h = hw / W;
    int wc = hw - h * W;
    int cb = b * 255 + a * 85;
    const float* cls_base = p + (size_t)(cb + 5) * HW + hw;
    float bestv = cls_base[0];
    int bestc = 0;
#pragma unroll
    for (int c = 1; c < 80; ++c) {
        float v = cls_base[(size_t)c * HW];
        if (v > bestv) { bestv = v; bestc = c; }
    }
    float t0 = p[(size_t)(cb + 0) * HW + hw];
    float t1 = p[(size_t)(cb + 1) * HW + hw];
    float t2 = p[(size_t)(cb + 2) * HW + hw];
    float t3 = p[(size_t)(cb + 3) * HW + hw];
    float aw = (a == 0) ? aw0 : ((a == 1) ? aw1 : aw2);
    float ah = (a == 0) ? ah0 : ((a == 1) ? ah1 : ah2);
    float sx = sigm(t0);
    float sy = sigm(t1);
    float bw = aw * expf(t2);
    float bh = ah * expf(t3);
    float cx = ((float)wc + sx) * strideF;
    float cy = ((float)h + sy) * strideF;
    float w0 = bw * 0.5f, h0 = bh * 0.5f;
    row[0] = conf;
    row[1] = cx - w0;
    row[2] = cy - h0;
    row[3] = cx + w0;
    row[4] = cy + h0;
    row[5] = (float)bestc;
    row[6] = (float)b;
}

__global__ void __launch_bounds__(512) k_mega(const float* __restrict__ p13,
                                              const float* __restrict__ p26,
                                              const float* __restrict__ p52,
                                              const unsigned* __restrict__ cnt,
                                              const unsigned long long* __restrict__ keys,
                                              float* __restrict__ out) {
    __shared__ unsigned long long keysL[KMAX];       // 16 KB
    __shared__ unsigned long long sortedL[TOPK];     // 4 KB
    __shared__ float candL[TOPK * 7];                // 14 KB
    __shared__ unsigned long long smask[TOPK * 8];   // 32 KB
    __shared__ unsigned long long live[8], keepw[8];
    int tid = threadIdx.x;

    // ---- phase A: load keys, rank-select top-512 (round-0 K3 rank body, full-range store) ----
    unsigned n = *cnt; if (n > (unsigned)KMAX) n = (unsigned)KMAX;
    int npad = ((int)n + 7) & ~7;
    for (int j = tid; j < npad; j += 512) keysL[j] = (j < (int)n) ? keys[j] : 0ull;
    sortedL[tid] = 0ull;
    __syncthreads();
    unsigned long long mine[4]; unsigned rk[4]; int nown = 0;
#pragma unroll
    for (int k = 0; k < 4; ++k) {
        int idx = tid + k * 512;
        if (idx < (int)n) { mine[nown] = keysL[idx]; rk[nown] = 0u; ++nown; }
    }
    for (int j = 0; j < npad; j += 8) {              // 8-wide unroll: independent LDS loads
        unsigned long long kk[8];
#pragma unroll
        for (int u = 0; u < 8; ++u) kk[u] = keysL[j + u];
        for (int m = 0; m < nown; ++m) {
            unsigned acc = 0u;
#pragma unroll
            for (int u = 0; u < 8; ++u) acc += (kk[u] > mine[m]) ? 1u : 0u;
            rk[m] += acc;
        }
    }
    for (int m = 0; m < nown; ++m) {
        unsigned r = rk[m];
        if (r < (unsigned)TOPK) sortedL[r] = mine[m];  // keys unique -> ranks unique
    }
    __syncthreads();

    // ---- phase B: decode, thread-per-box ----
    {
        unsigned long long key = sortedL[tid];
        unsigned sb = (unsigned)(key >> 32);
        float* row = candL + tid * 7;
        if (sb == 0u) {
#pragma unroll
            for (int q = 0; q < 7; ++q) row[q] = 0.0f;
        } else {
            unsigned idx = 0xFFFFFFFFu - (unsigned)(key & 0xFFFFFFFFull);
            float conf = __uint_as_float(sb);
            if (idx < N13E)
                decode1<169, 13>(p13, (int)idx, 32.0f, 116.f, 90.f, 156.f, 198.f, 373.f, 326.f, conf, row);
            else if (idx < N13E + N26E)
                decode1<676, 26>(p26, (int)idx - BASE26, 16.0f, 30.f, 61.f, 62.f, 45.f, 59.f, 119.f, conf, row);
            else
                decode1<2704, 52>(p52, (int)idx - BASE52, 8.0f, 10.f, 13.f, 16.f, 30.f, 33.f, 23.f, conf, row);
        }
    }
    __syncthreads();

    // ---- phase C: suppression mask (round-0 K4 body, LDS-resident, zero-word skip) ----
    {
        int wv = tid >> 6;
        int lane = tid & 63;
        for (int word = wv; word < TOPK * 8; word += 8) {
            int i = word >> 3, jw = word & 7;
            if ((jw << 6) + 63 <= i) {               // all j <= i: word structurally zero
                if (lane == 0) smask[word] = 0ull;
                continue;
            }
            int j = (jw << 6) + lane;
            const float* ri = candL + i * 7;
            const float* rj = candL + j * 7;
            float ix1 = ri[1], iy1 = ri[2], ix2 = ri[3], iy2 = ri[4];
            float ai = fmaxf(ix2 - ix1, 0.f) * fmaxf(iy2 - iy1, 0.f);
            float jx1 = rj[1], jy1 = rj[2], jx2 = rj[3], jy2 = rj[4];
            float aj = fmaxf(jx2 - jx1, 0.f) * fmaxf(jy2 - jy1, 0.f);
            float xx1 = fmaxf(ix1, jx1), yy1 = fmaxf(iy1, jy1);
            float xx2 = fminf(ix2, jx2), yy2 = fminf(iy2, jy2);
            float inter = fmaxf(xx2 - xx1, 0.f) * fmaxf(yy2 - yy1, 0.f);
            float iou = inter / (((ai + aj) - inter) + 1e-9f);
            bool bit = (j > i) && (iou > 0.3f);
            unsigned long long m = __ballot(bit);
            if (lane == 0) smask[word] = m;
        }
    }
    // ---- phase D: live ballot + serial greedy sweep (round-0 K5 body, LDS-resident) ----
    bool validt = candL[tid * 7] > 0.5f;             // candL[tid*7] written pre-syncthreads above
    unsigned long long bal = __ballot(validt);
    if ((tid & 63) == 0) live[tid >> 6] = bal;
    __syncthreads();
    if (tid < 64) {
        int lane = tid;
        int lw = lane & 7;
        unsigned long long r = 0ull;
#pragma unroll
        for (int w = 0; w < 8; ++w) {
            unsigned long long lvw = live[w];
#pragma unroll 8
            for (int b2 = 0; b2 < 64; ++b2) {
                int i = w * 64 + b2;
                unsigned long long rowv = smask[i * 8 + lw];
                unsigned rlo = (unsigned)__builtin_amdgcn_readlane((int)(unsigned)(r & 0xFFFFFFFFull), w);
                unsigned rhi = (unsigned)__builtin_amdgcn_readlane((int)(unsigned)(r >> 32), w);
                unsigned long long rw = (((unsigned long long)rhi) << 32) | (unsigned long long)rlo;
                bool acc = (((lvw >> b2) & 1ull) != 0ull) && (((rw >> b2) & 1ull) == 0ull);
                if (acc) r |= rowv;
            }
        }
        if (lane < 8) keepw[lane] = live[lane] & ~r;
    }
    __syncthreads();
    for (int p = tid; p < TOPK * 7; p += 512) {
        int i = p / 7;
        unsigned long long kb = (keepw[i >> 6] >> (i & 63)) & 1ull;
        out[p] = kb ? candL[p] : 0.0f;
    }
}

// ---------------- launch: 4 nodes (memset + 3 kernels) ----------------
extern "C" void kernel_launch(void* const* d_in, const int* in_sizes, int n_in,
                              void* d_out, int out_size, void* d_ws, size_t ws_size,
                              hipStream_t stream) {
    const float* p13 = (const float*)d_in[0];
    const float* p26 = (const float*)d_in[1];
    const float* p52 = (const float*)d_in[2];
    float* out = (float*)d_out;
    char* ws = (char*)d_ws;

    unsigned* hist           = (unsigned*)(ws + 0);                // 2048 u32
    unsigned* cnt            = (unsigned*)(ws + 8192);             // 1 u32
    unsigned long long* keys = (unsigned long long*)(ws + 8704);   // 2048 u64

    hipMemsetAsync(ws, 0, 8196, stream);   // zero hist + cnt

    int gh = (NTOT + 255) / 256;   // 1331
    int gc = (NTOT + 511) / 512;   // 666
    k_hist<<<gh, 256, 0, stream>>>(p13, p26, p52, hist);
    k_compact_scan<<<gc, 512, 0, stream>>>(p13, p26, p52, hist, cnt, keys);
    k_mega<<<1, 512, 0, stream>>>(p13, p26, p52, cnt, keys, out);
}

// Round 3
// 351.333 us; speedup vs baseline: 1.2721x; 1.2721x over previous
//
#include <hip/hip_runtime.h>

// ---------------- problem constants ----------------
#define N13E 16224      // 32*3*169
#define N26E 64896      // 32*3*676
#define NTOT 340704
#define BASE26 16224
#define BASE52 81120
#define KMAX 2048
#define TOPK 512

__device__ __forceinline__ float sigm(float x) { return 1.0f / (1.0f + expf(-x)); }

// ================= K1: histogram of conf bits (R0-validated verbatim) =================
template <int HW>
__device__ __forceinline__ float load_logit(const float* __restrict__ p, int local) {
    int ba = local / HW;           // b*3 + a
    int hw = local - ba * HW;
    int b = ba / 3;
    int a = ba - b * 3;
    return p[(b * 255 + a * 85 + 4) * HW + hw];
}

__global__ void __launch_bounds__(256) k_hist(const float* __restrict__ p13,
                                              const float* __restrict__ p26,
                                              const float* __restrict__ p52,
                                              unsigned* __restrict__ hist) {
    int t = blockIdx.x * 256 + threadIdx.x;
    if (t >= NTOT) return;
    float logit;
    if (t < N13E)               logit = load_logit<169>(p13, t);
    else if (t < N13E + N26E)   logit = load_logit<676>(p26, t - N13E);
    else                        logit = load_logit<2704>(p52, t - (N13E + N26E));
    float conf = sigm(logit);
    if (conf > 0.5f) {
        unsigned bin = (__float_as_uint(conf) >> 12) - 0x3F000u;
        bin = (bin > 2047u) ? 2047u : bin;
        atomicAdd(&hist[bin], 1u);
    }
}

// ================= K2: threshold scan + compact + IN-PLACE DECODE =================
// The pushing thread owns (b,a,hw): it decodes its own box immediately.
// Scattered class-channel fetch is thereby spread over all 666 blocks (R2 lesson:
// single-CU scattered fetch caps at ~10 GB/s). Decode math = R2-validated decode1.
template <int HW, int W, int BASE>
__device__ __forceinline__ void compact_decode_one(const float* __restrict__ p, int local, unsigned thrv,
                                                   float strideF,
                                                   float aw0, float ah0, float aw1, float ah1,
                                                   float aw2, float ah2,
                                                   unsigned* __restrict__ cnt,
                                                   unsigned long long* __restrict__ keys,
                                                   float* __restrict__ candAll) {
    int ba = local / HW;
    int hw = local - ba * HW;
    int b = ba / 3;
    int a = ba - b * 3;
    float logit = p[(b * 255 + a * 85 + 4) * HW + hw];
    float conf = sigm(logit);
    unsigned bits = __float_as_uint(conf);
    if (conf > 0.5f && bits >= thrv) {
        unsigned pos = atomicAdd(cnt, 1u);
        if (pos < (unsigned)KMAX) {
            unsigned concat = (unsigned)(BASE + (b * HW + hw) * 3 + a);
            keys[pos] = (((unsigned long long)bits) << 32) | (unsigned long long)(0xFFFFFFFFu - concat);
            // ---- decode this element (R2-validated decode1 body) ----
            int h = hw / W;
            int wc = hw - h * W;
            int cb = b * 255 + a * 85;
            const float* cls_base = p + (size_t)(cb + 5) * HW + hw;
            float bestv = cls_base[0];
            int bestc = 0;
#pragma unroll
            for (int c = 1; c < 80; ++c) {
                float v = cls_base[(size_t)c * HW];
                if (v > bestv) { bestv = v; bestc = c; }
            }
            float t0 = p[(size_t)(cb + 0) * HW + hw];
            float t1 = p[(size_t)(cb + 1) * HW + hw];
            float t2 = p[(size_t)(cb + 2) * HW + hw];
            float t3 = p[(size_t)(cb + 3) * HW + hw];
            float aw = (a == 0) ? aw0 : ((a == 1) ? aw1 : aw2);
            float ah = (a == 0) ? ah0 : ((a == 1) ? ah1 : ah2);
            float sx = sigm(t0);
            float sy = sigm(t1);
            float bw = aw * expf(t2);
            float bh = ah * expf(t3);
            float cx = ((float)wc + sx) * strideF;
            float cy = ((float)h + sy) * strideF;
            float w0 = bw * 0.5f, h0 = bh * 0.5f;
            float* row = candAll + pos * 7;
            row[0] = conf;
            row[1] = cx - w0;
            row[2] = cy - h0;
            row[3] = cx + w0;
            row[4] = cy + h0;
            row[5] = (float)bestc;
            row[6] = (float)b;
        }
    }
}

__global__ void __launch_bounds__(512) k_compact_scan_decode(const float* __restrict__ p13,
                                                             const float* __restrict__ p26,
                                                             const float* __restrict__ p52,
                                                             const unsigned* __restrict__ hist,
                                                             unsigned* __restrict__ cnt,
                                                             unsigned long long* __restrict__ keys,
                                                             float* __restrict__ candAll) {
    __shared__ unsigned tot[512];
    __shared__ unsigned thrS;
    int tid = threadIdx.x;

    // ---- threshold scan (R0-validated verbatim) ----
    unsigned loc[4]; unsigned s = 0u;
#pragma unroll
    for (int k = 0; k < 4; ++k) { loc[k] = hist[2047 - (tid * 4 + k)]; s += loc[k]; }
    tot[tid] = s;
    __syncthreads();
    for (int off = 1; off < 512; off <<= 1) {
        unsigned u = (tid >= off) ? tot[tid - off] : 0u;
        __syncthreads();
        tot[tid] += u;
        __syncthreads();
    }
    unsigned excl = tot[tid] - s;
    unsigned total = tot[511];
    if (total < (unsigned)TOPK) {
        if (tid == 0) thrS = 0x3F000001u;     // accept every conf > 0.5
    } else {
        unsigned run = excl;
#pragma unroll
        for (int k = 0; k < 4; ++k) {
            unsigned c = run + loc[k];
            if (run < (unsigned)TOPK && c >= (unsigned)TOPK) {  // unique crossing
                int bin = 2047 - (tid * 4 + k);
                thrS = ((unsigned)(bin + 0x3F000)) << 12;
            }
            run = c;
        }
    }
    __syncthreads();
    unsigned thrv = thrS;

    int t = blockIdx.x * 512 + tid;
    if (t >= NTOT) return;
    if (t < N13E)
        compact_decode_one<169, 13, 0>(p13, t, thrv, 32.0f,
                                       116.f, 90.f, 156.f, 198.f, 373.f, 326.f, cnt, keys, candAll);
    else if (t < N13E + N26E)
        compact_decode_one<676, 26, BASE26>(p26, t - N13E, thrv, 16.0f,
                                            30.f, 61.f, 62.f, 45.f, 59.f, 119.f, cnt, keys, candAll);
    else
        compact_decode_one<2704, 52, BASE52>(p52, t - (N13E + N26E), thrv, 8.0f,
                                             10.f, 13.f, 16.f, 30.f, 33.f, 23.f, cnt, keys, candAll);
}

// ================= K3 tail: rank + gather + mask + sweep, ONE block, LDS-local =================
__global__ void __launch_bounds__(512) k_tail(const unsigned* __restrict__ cnt,
                                              const unsigned long long* __restrict__ keys,
                                              const float* __restrict__ candAll,
                                              float* __restrict__ out) {
    __shared__ unsigned long long keysL[KMAX];       // 16 KB
    __shared__ unsigned long long sortedL[TOPK];     // 4 KB
    __shared__ unsigned short sortedIdxL[TOPK];      // 1 KB
    __shared__ float candL[TOPK * 7];                // 14 KB
    __shared__ unsigned long long smask[TOPK * 8];   // 32 KB
    __shared__ unsigned long long live[8], keepw[8];
    int tid = threadIdx.x;

    // ---- phase A: rank-select top-512 (R2-validated body + index tracking) ----
    unsigned n = *cnt; if (n > (unsigned)KMAX) n = (unsigned)KMAX;
    int npad = ((int)n + 7) & ~7;
    for (int j = tid; j < npad; j += 512) keysL[j] = (j < (int)n) ? keys[j] : 0ull;
    sortedL[tid] = 0ull;
    __syncthreads();
    unsigned long long mine[4]; unsigned rk[4]; int nown = 0;
#pragma unroll
    for (int k = 0; k < 4; ++k) {
        int idx = tid + k * 512;
        if (idx < (int)n) { mine[nown] = keysL[idx]; rk[nown] = 0u; ++nown; }
    }
    for (int j = 0; j < npad; j += 8) {              // 8-wide unroll: independent LDS loads
        unsigned long long kk[8];
#pragma unroll
        for (int u = 0; u < 8; ++u) kk[u] = keysL[j + u];
        for (int m = 0; m < nown; ++m) {
            unsigned acc = 0u;
#pragma unroll
            for (int u = 0; u < 8; ++u) acc += (kk[u] > mine[m]) ? 1u : 0u;
            rk[m] += acc;
        }
    }
    for (int m = 0; m < nown; ++m) {
        unsigned r = rk[m];
        if (r < (unsigned)TOPK) {                    // keys unique -> ranks unique
            sortedL[r] = mine[m];
            sortedIdxL[r] = (unsigned short)(tid + m * 512);  // m-th owned index is tid + m*512
        }
    }
    __syncthreads();

    // ---- phase B: gather pre-decoded rows (L2-hot, no scattered HBM fetch) ----
    {
        unsigned long long key = sortedL[tid];
        float* row = candL + tid * 7;
        if ((unsigned)(key >> 32) == 0u) {
#pragma unroll
            for (int q = 0; q < 7; ++q) row[q] = 0.0f;
        } else {
            const float* src = candAll + (int)sortedIdxL[tid] * 7;
#pragma unroll
            for (int q = 0; q < 7; ++q) row[q] = src[q];
        }
    }
    __syncthreads();

    // ---- phase C: suppression mask (R2-validated body, zero-word skip) ----
    {
        int wv = tid >> 6;
        int lane = tid & 63;
        for (int word = wv; word < TOPK * 8; word += 8) {
            int i = word >> 3, jw = word & 7;
            if ((jw << 6) + 63 <= i) {               // all j <= i: word structurally zero
                if (lane == 0) smask[word] = 0ull;
                continue;
            }
            int j = (jw << 6) + lane;
            const float* ri = candL + i * 7;
            const float* rj = candL + j * 7;
            float ix1 = ri[1], iy1 = ri[2], ix2 = ri[3], iy2 = ri[4];
            float ai = fmaxf(ix2 - ix1, 0.f) * fmaxf(iy2 - iy1, 0.f);
            float jx1 = rj[1], jy1 = rj[2], jx2 = rj[3], jy2 = rj[4];
            float aj = fmaxf(jx2 - jx1, 0.f) * fmaxf(jy2 - jy1, 0.f);
            float xx1 = fmaxf(ix1, jx1), yy1 = fmaxf(iy1, jy1);
            float xx2 = fminf(ix2, jx2), yy2 = fminf(iy2, jy2);
            float inter = fmaxf(xx2 - xx1, 0.f) * fmaxf(yy2 - yy1, 0.f);
            float iou = inter / (((ai + aj) - inter) + 1e-9f);
            bool bit = (j > i) && (iou > 0.3f);
            unsigned long long m = __ballot(bit);
            if (lane == 0) smask[word] = m;
        }
    }
    // ---- phase D: live ballot + serial greedy sweep (R2-validated body) ----
    bool validt = candL[tid * 7] > 0.5f;
    unsigned long long bal = __ballot(validt);
    if ((tid & 63) == 0) live[tid >> 6] = bal;
    __syncthreads();
    if (tid < 64) {
        int lane = tid;
        int lw = lane & 7;
        unsigned long long r = 0ull;
#pragma unroll
        for (int w = 0; w < 8; ++w) {
            unsigned long long lvw = live[w];
#pragma unroll 8
            for (int b2 = 0; b2 < 64; ++b2) {
                int i = w * 64 + b2;
                unsigned long long rowv = smask[i * 8 + lw];
                unsigned rlo = (unsigned)__builtin_amdgcn_readlane((int)(unsigned)(r & 0xFFFFFFFFull), w);
                unsigned rhi = (unsigned)__builtin_amdgcn_readlane((int)(unsigned)(r >> 32), w);
                unsigned long long rw = (((unsigned long long)rhi) << 32) | (unsigned long long)rlo;
                bool acc = (((lvw >> b2) & 1ull) != 0ull) && (((rw >> b2) & 1ull) == 0ull);
                if (acc) r |= rowv;
            }
        }
        if (lane < 8) keepw[lane] = live[lane] & ~r;
    }
    __syncthreads();
    for (int p = tid; p < TOPK * 7; p += 512) {
        int i = p / 7;
        unsigned long long kb = (keepw[i >> 6] >> (i & 63)) & 1ull;
        out[p] = kb ? candL[p] : 0.0f;
    }
}

// ---------------- launch: 4 nodes (memset + 3 kernels) ----------------
extern "C" void kernel_launch(void* const* d_in, const int* in_sizes, int n_in,
                              void* d_out, int out_size, void* d_ws, size_t ws_size,
                              hipStream_t stream) {
    const float* p13 = (const float*)d_in[0];
    const float* p26 = (const float*)d_in[1];
    const float* p52 = (const float*)d_in[2];
    float* out = (float*)d_out;
    char* ws = (char*)d_ws;

    unsigned* hist           = (unsigned*)(ws + 0);                // 2048 u32
    unsigned* cnt            = (unsigned*)(ws + 8192);             // 1 u32
    unsigned long long* keys = (unsigned long long*)(ws + 8704);   // 2048 u64
    float* candAll           = (float*)(ws + 25088);               // 2048*7 f32 = 57344 B

    hipMemsetAsync(ws, 0, 8196, stream);   // zero hist + cnt

    int gh = (NTOT + 255) / 256;   // 1331
    int gc = (NTOT + 511) / 512;   // 666
    k_hist<<<gh, 256, 0, stream>>>(p13, p26, p52, hist);
    k_compact_scan_decode<<<gc, 512, 0, stream>>>(p13, p26, p52, hist, cnt, keys, candAll);
    k_tail<<<1, 512, 0, stream>>>(cnt, keys, candAll, out);
}

// Round 5
// 233.537 us; speedup vs baseline: 1.9138x; 1.5044x over previous
//
#include <hip/hip_runtime.h>

// ---------------- problem constants ----------------
#define N13E 16224      // 32*3*169
#define N26E 64896      // 32*3*676
#define NTOT 340704
#define BASE26 16224
#define BASE52 81120
#define KMAX 2048
#define TOPK 512

__device__ __forceinline__ float sigm(float x) { return 1.0f / (1.0f + expf(-x)); }

// ================= K1: histogram of conf bits (R0-validated verbatim) =================
template <int HW>
__device__ __forceinline__ float load_logit(const float* __restrict__ p, int local) {
    int ba = local / HW;           // b*3 + a
    int hw = local - ba * HW;
    int b = ba / 3;
    int a = ba - b * 3;
    return p[(b * 255 + a * 85 + 4) * HW + hw];
}

__global__ void __launch_bounds__(256) k_hist(const float* __restrict__ p13,
                                              const float* __restrict__ p26,
                                              const float* __restrict__ p52,
                                              unsigned* __restrict__ hist) {
    int t = blockIdx.x * 256 + threadIdx.x;
    if (t >= NTOT) return;
    float logit;
    if (t < N13E)               logit = load_logit<169>(p13, t);
    else if (t < N13E + N26E)   logit = load_logit<676>(p26, t - N13E);
    else                        logit = load_logit<2704>(p52, t - (N13E + N26E));
    float conf = sigm(logit);
    if (conf > 0.5f) {
        unsigned bin = (__float_as_uint(conf) >> 12) - 0x3F000u;
        bin = (bin > 2047u) ? 2047u : bin;
        atomicAdd(&hist[bin], 1u);
    }
}

// ================= K2: threshold scan + compact + in-place decode (R3-validated verbatim) =================
template <int HW, int W, int BASE>
__device__ __forceinline__ void compact_decode_one(const float* __restrict__ p, int local, unsigned thrv,
                                                   float strideF,
                                                   float aw0, float ah0, float aw1, float ah1,
                                                   float aw2, float ah2,
                                                   unsigned* __restrict__ cnt,
                                                   unsigned long long* __restrict__ keys,
                                                   float* __restrict__ candAll) {
    int ba = local / HW;
    int hw = local - ba * HW;
    int b = ba / 3;
    int a = ba - b * 3;
    float logit = p[(b * 255 + a * 85 + 4) * HW + hw];
    float conf = sigm(logit);
    unsigned bits = __float_as_uint(conf);
    if (conf > 0.5f && bits >= thrv) {
        unsigned pos = atomicAdd(cnt, 1u);
        if (pos < (unsigned)KMAX) {
            unsigned concat = (unsigned)(BASE + (b * HW + hw) * 3 + a);
            keys[pos] = (((unsigned long long)bits) << 32) | (unsigned long long)(0xFFFFFFFFu - concat);
            int h = hw / W;
            int wc = hw - h * W;
            int cb = b * 255 + a * 85;
            const float* cls_base = p + (size_t)(cb + 5) * HW + hw;
            float bestv = cls_base[0];
            int bestc = 0;
#pragma unroll
            for (int c = 1; c < 80; ++c) {
                float v = cls_base[(size_t)c * HW];
                if (v > bestv) { bestv = v; bestc = c; }
            }
            float t0 = p[(size_t)(cb + 0) * HW + hw];
            float t1 = p[(size_t)(cb + 1) * HW + hw];
            float t2 = p[(size_t)(cb + 2) * HW + hw];
            float t3 = p[(size_t)(cb + 3) * HW + hw];
            float aw = (a == 0) ? aw0 : ((a == 1) ? aw1 : aw2);
            float ah = (a == 0) ? ah0 : ((a == 1) ? ah1 : ah2);
            float sx = sigm(t0);
            float sy = sigm(t1);
            float bw = aw * expf(t2);
            float bh = ah * expf(t3);
            float cx = ((float)wc + sx) * strideF;
            float cy = ((float)h + sy) * strideF;
            float w0 = bw * 0.5f, h0 = bh * 0.5f;
            float* row = candAll + pos * 7;
            row[0] = conf;
            row[1] = cx - w0;
            row[2] = cy - h0;
            row[3] = cx + w0;
            row[4] = cy + h0;
            row[5] = (float)bestc;
            row[6] = (float)b;
        }
    }
}

__global__ void __launch_bounds__(512) k_compact_scan_decode(const float* __restrict__ p13,
                                                             const float* __restrict__ p26,
                                                             const float* __restrict__ p52,
                                                             const unsigned* __restrict__ hist,
                                                             unsigned* __restrict__ cnt,
                                                             unsigned long long* __restrict__ keys,
                                                             float* __restrict__ candAll) {
    __shared__ unsigned tot[512];
    __shared__ unsigned thrS;
    int tid = threadIdx.x;

    unsigned loc[4]; unsigned s = 0u;
#pragma unroll
    for (int k = 0; k < 4; ++k) { loc[k] = hist[2047 - (tid * 4 + k)]; s += loc[k]; }
    tot[tid] = s;
    __syncthreads();
    for (int off = 1; off < 512; off <<= 1) {
        unsigned u = (tid >= off) ? tot[tid - off] : 0u;
        __syncthreads();
        tot[tid] += u;
        __syncthreads();
    }
    unsigned excl = tot[tid] - s;
    unsigned total = tot[511];
    if (total < (unsigned)TOPK) {
        if (tid == 0) thrS = 0x3F000001u;     // accept every conf > 0.5
    } else {
        unsigned run = excl;
#pragma unroll
        for (int k = 0; k < 4; ++k) {
            unsigned c = run + loc[k];
            if (run < (unsigned)TOPK && c >= (unsigned)TOPK) {  // unique crossing
                int bin = 2047 - (tid * 4 + k);
                thrS = ((unsigned)(bin + 0x3F000)) << 12;
            }
            run = c;
        }
    }
    __syncthreads();
    unsigned thrv = thrS;

    int t = blockIdx.x * 512 + tid;
    if (t >= NTOT) return;
    if (t < N13E)
        compact_decode_one<169, 13, 0>(p13, t, thrv, 32.0f,
                                       116.f, 90.f, 156.f, 198.f, 373.f, 326.f, cnt, keys, candAll);
    else if (t < N13E + N26E)
        compact_decode_one<676, 26, BASE26>(p26, t - N13E, thrv, 16.0f,
                                            30.f, 61.f, 62.f, 45.f, 59.f, 119.f, cnt, keys, candAll);
    else
        compact_decode_one<2704, 52, BASE52>(p52, t - (N13E + N26E), thrv, 8.0f,
                                             10.f, 13.f, 16.f, 30.f, 33.f, 23.f, cnt, keys, candAll);
}

// ================= K3: rank + gather + mask, 32 blocks =================
// Each block redundantly computes the full top-512 rank+gather in its own LDS
// (n ~ 520 keys: cheap, L2-hot), then computes its 1/32 slice of the suppression
// mask with R0's validated distribution: 8 waves x 16 words, fully unrolled, no
// skip-branch (R3 lesson: the branchy single-block loop was latency-bound, 180 us).
__global__ void __launch_bounds__(512) k_rank_gather_mask(const unsigned* __restrict__ cnt,
                                                          const unsigned long long* __restrict__ keys,
                                                          const float* __restrict__ candAll,
                                                          float* __restrict__ candSorted,
                                                          unsigned long long* __restrict__ smaskG) {
    __shared__ unsigned long long keysL[KMAX];       // 16 KB
    __shared__ unsigned long long sortedL[TOPK];     // 4 KB
    __shared__ unsigned short sortedIdxL[TOPK];      // 1 KB
    __shared__ float candL[TOPK * 7];                // 14 KB
    int tid = threadIdx.x;

    // ---- rank-select top-512 (R2/R3-validated body) ----
    unsigned n = *cnt; if (n > (unsigned)KMAX) n = (unsigned)KMAX;
    int npad = ((int)n + 7) & ~7;
    for (int j = tid; j < npad; j += 512) keysL[j] = (j < (int)n) ? keys[j] : 0ull;
    sortedL[tid] = 0ull;
    __syncthreads();
    unsigned long long mine[4]; unsigned rk[4]; int nown = 0;
#pragma unroll
    for (int k = 0; k < 4; ++k) {
        int idx = tid + k * 512;
        if (idx < (int)n) { mine[nown] = keysL[idx]; rk[nown] = 0u; ++nown; }
    }
    for (int j = 0; j < npad; j += 8) {              // 8-wide unroll: independent LDS loads
        unsigned long long kk[8];
#pragma unroll
        for (int u = 0; u < 8; ++u) kk[u] = keysL[j + u];
        for (int m = 0; m < nown; ++m) {
            unsigned acc = 0u;
#pragma unroll
            for (int u = 0; u < 8; ++u) acc += (kk[u] > mine[m]) ? 1u : 0u;
            rk[m] += acc;
        }
    }
    for (int m = 0; m < nown; ++m) {
        unsigned r = rk[m];
        if (r < (unsigned)TOPK) {                    // keys unique -> ranks unique
            sortedL[r] = mine[m];
            sortedIdxL[r] = (unsigned short)(tid + m * 512);
        }
    }
    __syncthreads();

    // ---- gather pre-decoded rows (R3-validated body) ----
    {
        unsigned long long key = sortedL[tid];
        float* row = candL + tid * 7;
        if ((unsigned)(key >> 32) == 0u) {
#pragma unroll
            for (int q = 0; q < 7; ++q) row[q] = 0.0f;
        } else {
            const float* src = candAll + (int)sortedIdxL[tid] * 7;
#pragma unroll
            for (int q = 0; q < 7; ++q) row[q] = src[q];
        }
    }
    __syncthreads();

    // block 0 publishes candSorted for k_sweep (no barrier needed: different memory)
    if (blockIdx.x == 0) {
        for (int p = tid; p < TOPK * 7; p += 512) candSorted[p] = candL[p];
    }

    // ---- mask slice: R0-validated distribution (8 waves x 16 words, unrolled) ----
    int wv = tid >> 6;
    int lane = tid & 63;
    int gwave = blockIdx.x * 8 + wv;          // 0..255
#pragma unroll
    for (int q = 0; q < 16; ++q) {
        int word = gwave * 16 + q;            // 0..4095
        int i = word >> 3, jw = word & 7;
        int j = jw * 64 + lane;
        const float* ri = candL + i * 7;
        const float* rj = candL + j * 7;
        float ix1 = ri[1], iy1 = ri[2], ix2 = ri[3], iy2 = ri[4];
        float ai = fmaxf(ix2 - ix1, 0.f) * fmaxf(iy2 - iy1, 0.f);
        float jx1 = rj[1], jy1 = rj[2], jx2 = rj[3], jy2 = rj[4];
        float aj = fmaxf(jx2 - jx1, 0.f) * fmaxf(jy2 - jy1, 0.f);
        float xx1 = fmaxf(ix1, jx1), yy1 = fmaxf(iy1, jy1);
        float xx2 = fminf(ix2, jx2), yy2 = fminf(iy2, jy2);
        float inter = fmaxf(xx2 - xx1, 0.f) * fmaxf(yy2 - yy1, 0.f);
        float iou = inter / (((ai + aj) - inter) + 1e-9f);
        bool bit = (j > i) && (iou > 0.3f);
        unsigned long long m = __ballot(bit);
        if (lane == 0) smaskG[word] = m;
    }
}

// ================= K4: serial greedy sweep + masked output, 1 block (R0-validated verbatim) =================
__global__ void __launch_bounds__(512) k_sweep(const float* __restrict__ cand,
                                               const unsigned long long* __restrict__ smaskG,
                                               float* __restrict__ out) {
    __shared__ unsigned long long smask[TOPK * 8];   // 32 KB
    __shared__ unsigned long long live[8], keepw[8];
    int tid = threadIdx.x;
    for (int p = tid; p < TOPK * 8; p += 512) smask[p] = smaskG[p];
    bool validt = cand[tid * 7] > 0.5f;
    unsigned long long bal = __ballot(validt);
    if ((tid & 63) == 0) live[tid >> 6] = bal;
    __syncthreads();
    if (tid < 64) {
        int lane = tid;
        int lw = lane & 7;
        unsigned long long r = 0ull;
#pragma unroll
        for (int w = 0; w < 8; ++w) {
            unsigned long long lvw = live[w];
#pragma unroll 8
            for (int b2 = 0; b2 < 64; ++b2) {
                int i = w * 64 + b2;
                unsigned long long rowv = smask[i * 8 + lw];
                unsigned rlo = (unsigned)__builtin_amdgcn_readlane((int)(unsigned)(r & 0xFFFFFFFFull), w);
                unsigned rhi = (unsigned)__builtin_amdgcn_readlane((int)(unsigned)(r >> 32), w);
                unsigned long long rw = (((unsigned long long)rhi) << 32) | (unsigned long long)rlo;
                bool acc = (((lvw >> b2) & 1ull) != 0ull) && (((rw >> b2) & 1ull) == 0ull);
                if (acc) r |= rowv;
            }
        }
        if (lane < 8) keepw[lane] = live[lane] & ~r;
    }
    __syncthreads();
    for (int p = tid; p < TOPK * 7; p += 512) {
        int i = p / 7;
        unsigned long long kb = (keepw[i >> 6] >> (i & 63)) & 1ull;
        out[p] = kb ? cand[p] : 0.0f;
    }
}

// ---------------- launch: 5 nodes (memset + 4 kernels) ----------------
extern "C" void kernel_launch(void* const* d_in, const int* in_sizes, int n_in,
                              void* d_out, int out_size, void* d_ws, size_t ws_size,
                              hipStream_t stream) {
    const float* p13 = (const float*)d_in[0];
    const float* p26 = (const float*)d_in[1];
    const float* p52 = (const float*)d_in[2];
    float* out = (float*)d_out;
    char* ws = (char*)d_ws;

    unsigned* hist             = (unsigned*)(ws + 0);                // 2048 u32
    unsigned* cnt              = (unsigned*)(ws + 8192);             // 1 u32
    unsigned long long* keys   = (unsigned long long*)(ws + 8704);   // 2048 u64  -> ends 25088
    float* candAll             = (float*)(ws + 25088);               // 2048*7 f32 -> ends 82432
    float* candSorted          = (float*)(ws + 82432);               // 512*7 f32  -> ends 96768
    unsigned long long* smaskG = (unsigned long long*)(ws + 96768);  // 4096 u64   -> ends 129536

    hipMemsetAsync(ws, 0, 8196, stream);   // zero hist + cnt

    int gh = (NTOT + 255) / 256;   // 1331
    int gc = (NTOT + 511) / 512;   // 666
    k_hist<<<gh, 256, 0, stream>>>(p13, p26, p52, hist);
    k_compact_scan_decode<<<gc, 512, 0, stream>>>(p13, p26, p52, hist, cnt, keys, candAll);
    k_rank_gather_mask<<<32, 512, 0, stream>>>(cnt, keys, candAll, candSorted, smaskG);
    k_sweep<<<1, 512, 0, stream>>>(candSorted, smaskG, out);
}

// Round 6
// 209.024 us; speedup vs baseline: 2.1382x; 1.1173x over previous
//
#include <hip/hip_runtime.h>

// ---------------- problem constants ----------------
#define N13E 16224      // 32*3*169
#define N26E 64896      // 32*3*676
#define NTOT 340704
#define BASE26 16224
#define BASE52 81120
#define KMAX 2048
#define TOPK 512

__device__ __forceinline__ float sigm(float x) { return 1.0f / (1.0f + expf(-x)); }

// ================= K1: histogram of conf bits (R0-validated verbatim) =================
template <int HW>
__device__ __forceinline__ float load_logit(const float* __restrict__ p, int local) {
    int ba = local / HW;           // b*3 + a
    int hw = local - ba * HW;
    int b = ba / 3;
    int a = ba - b * 3;
    return p[(b * 255 + a * 85 + 4) * HW + hw];
}

__global__ void __launch_bounds__(256) k_hist(const float* __restrict__ p13,
                                              const float* __restrict__ p26,
                                              const float* __restrict__ p52,
                                              unsigned* __restrict__ hist) {
    int t = blockIdx.x * 256 + threadIdx.x;
    if (t >= NTOT) return;
    float logit;
    if (t < N13E)               logit = load_logit<169>(p13, t);
    else if (t < N13E + N26E)   logit = load_logit<676>(p26, t - N13E);
    else                        logit = load_logit<2704>(p52, t - (N13E + N26E));
    float conf = sigm(logit);
    if (conf > 0.5f) {
        unsigned bin = (__float_as_uint(conf) >> 12) - 0x3F000u;
        bin = (bin > 2047u) ? 2047u : bin;
        atomicAdd(&hist[bin], 1u);
    }
}

// ================= K2: threshold scan + compact + in-place decode (R3/R5-validated verbatim) =================
template <int HW, int W, int BASE>
__device__ __forceinline__ void compact_decode_one(const float* __restrict__ p, int local, unsigned thrv,
                                                   float strideF,
                                                   float aw0, float ah0, float aw1, float ah1,
                                                   float aw2, float ah2,
                                                   unsigned* __restrict__ cnt,
                                                   unsigned long long* __restrict__ keys,
                                                   float* __restrict__ candAll) {
    int ba = local / HW;
    int hw = local - ba * HW;
    int b = ba / 3;
    int a = ba - b * 3;
    float logit = p[(b * 255 + a * 85 + 4) * HW + hw];
    float conf = sigm(logit);
    unsigned bits = __float_as_uint(conf);
    if (conf > 0.5f && bits >= thrv) {
        unsigned pos = atomicAdd(cnt, 1u);
        if (pos < (unsigned)KMAX) {
            unsigned concat = (unsigned)(BASE + (b * HW + hw) * 3 + a);
            keys[pos] = (((unsigned long long)bits) << 32) | (unsigned long long)(0xFFFFFFFFu - concat);
            int h = hw / W;
            int wc = hw - h * W;
            int cb = b * 255 + a * 85;
            const float* cls_base = p + (size_t)(cb + 5) * HW + hw;
            float bestv = cls_base[0];
            int bestc = 0;
#pragma unroll
            for (int c = 1; c < 80; ++c) {
                float v = cls_base[(size_t)c * HW];
                if (v > bestv) { bestv = v; bestc = c; }
            }
            float t0 = p[(size_t)(cb + 0) * HW + hw];
            float t1 = p[(size_t)(cb + 1) * HW + hw];
            float t2 = p[(size_t)(cb + 2) * HW + hw];
            float t3 = p[(size_t)(cb + 3) * HW + hw];
            float aw = (a == 0) ? aw0 : ((a == 1) ? aw1 : aw2);
            float ah = (a == 0) ? ah0 : ((a == 1) ? ah1 : ah2);
            float sx = sigm(t0);
            float sy = sigm(t1);
            float bw = aw * expf(t2);
            float bh = ah * expf(t3);
            float cx = ((float)wc + sx) * strideF;
            float cy = ((float)h + sy) * strideF;
            float w0 = bw * 0.5f, h0 = bh * 0.5f;
            float* row = candAll + pos * 7;
            row[0] = conf;
            row[1] = cx - w0;
            row[2] = cy - h0;
            row[3] = cx + w0;
            row[4] = cy + h0;
            row[5] = (float)bestc;
            row[6] = (float)b;
        }
    }
}

__global__ void __launch_bounds__(512) k_compact_scan_decode(const float* __restrict__ p13,
                                                             const float* __restrict__ p26,
                                                             const float* __restrict__ p52,
                                                             const unsigned* __restrict__ hist,
                                                             unsigned* __restrict__ cnt,
                                                             unsigned long long* __restrict__ keys,
                                                             float* __restrict__ candAll) {
    __shared__ unsigned tot[512];
    __shared__ unsigned thrS;
    int tid = threadIdx.x;

    unsigned loc[4]; unsigned s = 0u;
#pragma unroll
    for (int k = 0; k < 4; ++k) { loc[k] = hist[2047 - (tid * 4 + k)]; s += loc[k]; }
    tot[tid] = s;
    __syncthreads();
    for (int off = 1; off < 512; off <<= 1) {
        unsigned u = (tid >= off) ? tot[tid - off] : 0u;
        __syncthreads();
        tot[tid] += u;
        __syncthreads();
    }
    unsigned excl = tot[tid] - s;
    unsigned total = tot[511];
    if (total < (unsigned)TOPK) {
        if (tid == 0) thrS = 0x3F000001u;     // accept every conf > 0.5
    } else {
        unsigned run = excl;
#pragma unroll
        for (int k = 0; k < 4; ++k) {
            unsigned c = run + loc[k];
            if (run < (unsigned)TOPK && c >= (unsigned)TOPK) {  // unique crossing
                int bin = 2047 - (tid * 4 + k);
                thrS = ((unsigned)(bin + 0x3F000)) << 12;
            }
            run = c;
        }
    }
    __syncthreads();
    unsigned thrv = thrS;

    int t = blockIdx.x * 512 + tid;
    if (t >= NTOT) return;
    if (t < N13E)
        compact_decode_one<169, 13, 0>(p13, t, thrv, 32.0f,
                                       116.f, 90.f, 156.f, 198.f, 373.f, 326.f, cnt, keys, candAll);
    else if (t < N13E + N26E)
        compact_decode_one<676, 26, BASE26>(p26, t - N13E, thrv, 16.0f,
                                            30.f, 61.f, 62.f, 45.f, 59.f, 119.f, cnt, keys, candAll);
    else
        compact_decode_one<2704, 52, BASE52>(p52, t - (N13E + N26E), thrv, 8.0f,
                                             10.f, 13.f, 16.f, 30.f, 33.f, 23.f, cnt, keys, candAll);
}

// ================= K3: rank + gather + mask, 32 blocks (R5-validated verbatim) =================
__global__ void __launch_bounds__(512) k_rank_gather_mask(const unsigned* __restrict__ cnt,
                                                          const unsigned long long* __restrict__ keys,
                                                          const float* __restrict__ candAll,
                                                          float* __restrict__ candSorted,
                                                          unsigned long long* __restrict__ smaskG) {
    __shared__ unsigned long long keysL[KMAX];       // 16 KB
    __shared__ unsigned long long sortedL[TOPK];     // 4 KB
    __shared__ unsigned short sortedIdxL[TOPK];      // 1 KB
    __shared__ float candL[TOPK * 7];                // 14 KB
    int tid = threadIdx.x;

    // ---- rank-select top-512 ----
    unsigned n = *cnt; if (n > (unsigned)KMAX) n = (unsigned)KMAX;
    int npad = ((int)n + 7) & ~7;
    for (int j = tid; j < npad; j += 512) keysL[j] = (j < (int)n) ? keys[j] : 0ull;
    sortedL[tid] = 0ull;
    __syncthreads();
    unsigned long long mine[4]; unsigned rk[4]; int nown = 0;
#pragma unroll
    for (int k = 0; k < 4; ++k) {
        int idx = tid + k * 512;
        if (idx < (int)n) { mine[nown] = keysL[idx]; rk[nown] = 0u; ++nown; }
    }
    for (int j = 0; j < npad; j += 8) {              // 8-wide unroll: independent LDS loads
        unsigned long long kk[8];
#pragma unroll
        for (int u = 0; u < 8; ++u) kk[u] = keysL[j + u];
        for (int m = 0; m < nown; ++m) {
            unsigned acc = 0u;
#pragma unroll
            for (int u = 0; u < 8; ++u) acc += (kk[u] > mine[m]) ? 1u : 0u;
            rk[m] += acc;
        }
    }
    for (int m = 0; m < nown; ++m) {
        unsigned r = rk[m];
        if (r < (unsigned)TOPK) {                    // keys unique -> ranks unique
            sortedL[r] = mine[m];
            sortedIdxL[r] = (unsigned short)(tid + m * 512);
        }
    }
    __syncthreads();

    // ---- gather pre-decoded rows ----
    {
        unsigned long long key = sortedL[tid];
        float* row = candL + tid * 7;
        if ((unsigned)(key >> 32) == 0u) {
#pragma unroll
            for (int q = 0; q < 7; ++q) row[q] = 0.0f;
        } else {
            const float* src = candAll + (int)sortedIdxL[tid] * 7;
#pragma unroll
            for (int q = 0; q < 7; ++q) row[q] = src[q];
        }
    }
    __syncthreads();

    // block 0 publishes candSorted for k_sweep
    if (blockIdx.x == 0) {
        for (int p = tid; p < TOPK * 7; p += 512) candSorted[p] = candL[p];
    }

    // ---- mask slice: 8 waves x 16 words, unrolled ----
    int wv = tid >> 6;
    int lane = tid & 63;
    int gwave = blockIdx.x * 8 + wv;          // 0..255
#pragma unroll
    for (int q = 0; q < 16; ++q) {
        int word = gwave * 16 + q;            // 0..4095
        int i = word >> 3, jw = word & 7;
        int j = jw * 64 + lane;
        const float* ri = candL + i * 7;
        const float* rj = candL + j * 7;
        float ix1 = ri[1], iy1 = ri[2], ix2 = ri[3], iy2 = ri[4];
        float ai = fmaxf(ix2 - ix1, 0.f) * fmaxf(iy2 - iy1, 0.f);
        float jx1 = rj[1], jy1 = rj[2], jx2 = rj[3], jy2 = rj[4];
        float aj = fmaxf(jx2 - jx1, 0.f) * fmaxf(jy2 - jy1, 0.f);
        float xx1 = fmaxf(ix1, jx1), yy1 = fmaxf(iy1, jy1);
        float xx2 = fminf(ix2, jx2), yy2 = fminf(iy2, jy2);
        float inter = fmaxf(xx2 - xx1, 0.f) * fmaxf(yy2 - yy1, 0.f);
        float iou = inter / (((ai + aj) - inter) + 1e-9f);
        bool bit = (j > i) && (iou > 0.3f);
        unsigned long long m = __ballot(bit);
        if (lane == 0) smaskG[word] = m;
    }
}

// ================= K4: Jacobi fixed-point NMS sweep + masked output, 1 block =================
// Greedy NMS keep-set is the UNIQUE fixed point of keep = live & ~OR_{j in keep} row_j
// (rows only contain bits j'>j -> dependency DAG; induction over box index proves any
// fixed point equals the greedy result, and Jacobi from keep=live converges in <=
// max-chain-depth iterations). Random boxes: chain depth ~2-4 -> ~3-5 iterations of
// fully-parallel work replaces the 512-step serial readlane chain (R5: ~7 us).
__global__ void __launch_bounds__(512) k_sweep(const float* __restrict__ cand,
                                               const unsigned long long* __restrict__ smaskG,
                                               float* __restrict__ out) {
    __shared__ unsigned long long smask[TOPK * 8];   // 32 KB
    __shared__ unsigned long long live[8], keepS[8], supS[8];
    __shared__ int changedS;
    int tid = threadIdx.x;
    int lane = tid & 63;
    int wv = tid >> 6;

    for (int p = tid; p < TOPK * 8; p += 512) smask[p] = smaskG[p];
    bool validt = cand[tid * 7] > 0.5f;
    unsigned long long bal = __ballot(validt);
    if (lane == 0) { live[wv] = bal; keepS[wv] = bal; }
    __syncthreads();

    for (;;) {
        // snapshot keep words (broadcast reads, conflict-free)
        unsigned long long kw[8];
#pragma unroll
        for (int k = 0; k < 8; ++k) kw[k] = keepS[k];
        // wave wv computes suppression word wv; lane handles j = lane + 64k
        // (adjacent lanes stride 64 B in smask -> 2-way bank aliasing, free)
        unsigned long long r = 0ull;
#pragma unroll
        for (int k = 0; k < 8; ++k) {
            int j = lane + (k << 6);
            unsigned long long m = smask[j * 8 + wv];
            unsigned long long kbit = (kw[k] >> lane) & 1ull;
            r |= m & (0ull - kbit);
        }
#pragma unroll
        for (int off = 32; off >= 1; off >>= 1) r |= __shfl_xor(r, off, 64);
        if (lane == 0) supS[wv] = r;
        __syncthreads();                  // supS complete; all snapshots taken
        if (tid == 0) changedS = 0;
        __syncthreads();                  // reset visible before updates
        if (tid < 8) {
            unsigned long long nk = live[tid] & ~supS[tid];
            if (nk != keepS[tid]) { keepS[tid] = nk; changedS = 1; }
        }
        __syncthreads();                  // keepS/changedS final for this iter
        if (!changedS) break;             // no change == fixed point == greedy
    }

    for (int p = tid; p < TOPK * 7; p += 512) {
        int i = p / 7;
        unsigned long long kb = (keepS[i >> 6] >> (i & 63)) & 1ull;
        out[p] = kb ? cand[p] : 0.0f;
    }
}

// ---------------- launch: 5 nodes (memset + 4 kernels) ----------------
extern "C" void kernel_launch(void* const* d_in, const int* in_sizes, int n_in,
                              void* d_out, int out_size, void* d_ws, size_t ws_size,
                              hipStream_t stream) {
    const float* p13 = (const float*)d_in[0];
    const float* p26 = (const float*)d_in[1];
    const float* p52 = (const float*)d_in[2];
    float* out = (float*)d_out;
    char* ws = (char*)d_ws;

    unsigned* hist             = (unsigned*)(ws + 0);                // 2048 u32
    unsigned* cnt              = (unsigned*)(ws + 8192);             // 1 u32
    unsigned long long* keys   = (unsigned long long*)(ws + 8704);   // 2048 u64  -> ends 25088
    float* candAll             = (float*)(ws + 25088);               // 2048*7 f32 -> ends 82432
    float* candSorted          = (float*)(ws + 82432);               // 512*7 f32  -> ends 96768
    unsigned long long* smaskG = (unsigned long long*)(ws + 96768);  // 4096 u64   -> ends 129536

    hipMemsetAsync(ws, 0, 8196, stream);   // zero hist + cnt

    int gh = (NTOT + 255) / 256;   // 1331
    int gc = (NTOT + 511) / 512;   // 666
    k_hist<<<gh, 256, 0, stream>>>(p13, p26, p52, hist);
    k_compact_scan_decode<<<gc, 512, 0, stream>>>(p13, p26, p52, hist, cnt, keys, candAll);
    k_rank_gather_mask<<<32, 512, 0, stream>>>(cnt, keys, candAll, candSorted, smaskG);
    k_sweep<<<1, 512, 0, stream>>>(candSorted, smaskG, out);
}